// Round 4
// baseline (132.070 us; speedup 1.0000x reference)
//
#include <hip/hip_runtime.h>
#include <hip/hip_bf16.h>

// QuIP#-style quantized linear. R14: dispatch-count reduction, 5 -> 3.
// qgemm (46.5us) is at its structural gather wall: 8 nulls (occupancy x2.2,
// depth x4, L1/sc0/mixed, KSPLIT, idx-coalescing) pin it at 32768 random
// 16B gathers/CU x ~3.4cy/request. Untouched (R11 champion verbatim).
// The ~81us residual is 4 tiny kernels (~15MB traffic total, trivial FLOPs)
// = fixed per-dispatch cost x5 + latency-bound bodies. R14 keeps R13's
// 8x-parallel FWHT factorization (H8192 = H8 (x) H1024, butterflies
// commute) but fuses the H8 pass INTO the H1024 kernels: each chunk-block
// recomputes the ±sign combination of H8 row `ch` from the full token row
// (8 L2-resident reads + 8 fma per element; x re-read 8x = 8MB L2, zpart
// re-read 8x = 32MB L2 ~= 1us). prep: 768 blocks (512 cvt + 256 fwht).
// zsum: 256 blocks (ks-sum + H8-combine + FWHT-1024 + scale).

typedef __attribute__((ext_vector_type(16))) float f32x16;
typedef __attribute__((ext_vector_type(8))) __bf16 bf16x8;
typedef __attribute__((ext_vector_type(4))) __bf16 bf16x4;
typedef __attribute__((ext_vector_type(4))) int i32x4;

#define IN_F 8192
#define OUT_F 8192
#define TOKENS 32
#define KSPLIT 8
#define KCHUNK 1024
#define CH (KCHUNK / 8)            // 128 16B-chunks per token row in LDS
#define GROUPS (KCHUNK / 32)       // 32 pipeline groups (4 codes each)
#define DG 5                       // gather lookahead (groups)
#define DI 7                       // idx lookahead (groups)
#define INV_SQRT_8192 0.011048543456039806f
#define PAD(i) ((i) + ((i) >> 5))

#if __has_builtin(__builtin_amdgcn_raw_buffer_load_b128) && \
    __has_builtin(__builtin_amdgcn_make_buffer_rsrc)
#define HAVE_BUF 1
#else
#define HAVE_BUF 0
#endif

// ---- FWHT-1024 (bits 0-9), 256 threads, radix-4, 5 stages --------------
// entry: v[j] = element 4*tid+j. exit: v[j] = element tid + j*256.
__device__ inline void fwht1024(float v[4], float* st, int tid) {
    {   // stage 0 (bits 0-1) in registers
        float t0 = v[0] + v[1], t1 = v[0] - v[1];
        float t2 = v[2] + v[3], t3 = v[2] - v[3];
        v[0] = t0 + t2; v[1] = t1 + t3; v[2] = t0 - t2; v[3] = t1 - t3;
    }
    int pos[4] = {4 * tid, 4 * tid + 1, 4 * tid + 2, 4 * tid + 3};
    #pragma unroll
    for (int s = 1; s < 5; ++s) {
        #pragma unroll
        for (int j = 0; j < 4; ++j) st[PAD(pos[j])] = v[j];
        __syncthreads();
        const int q = 1 << (2 * s);
        const int i = ((tid >> (2 * s)) << (2 * s + 2)) + (tid & (q - 1));
        #pragma unroll
        for (int j = 0; j < 4; ++j) { pos[j] = i + j * q; v[j] = st[PAD(pos[j])]; }
        __syncthreads();   // protect next stage's writes (WAR)
        float t0 = v[0] + v[1], t1 = v[0] - v[1];
        float t2 = v[2] + v[3], t3 = v[2] - v[3];
        v[0] = t0 + t2; v[1] = t1 + t3; v[2] = t0 - t2; v[3] = t1 - t3;
    }
}

// ---- kernel 1: codebook cvt (blocks<512) + fused H8+H1024 input FWHT ----
__global__ __launch_bounds__(256)
void prep_kernel(const float* __restrict__ cb, __bf16* __restrict__ cbb,
                 const float* __restrict__ x, const float* __restrict__ su,
                 __bf16* __restrict__ xh) {
    __shared__ float st[1056];
    const int tid = threadIdx.x;
    if (blockIdx.x < 512) {
        int i = blockIdx.x * 256 + tid;
        float4 vv = ((const float4*)cb)[i];
        bf16x4 o;
        o[0] = (__bf16)vv.x; o[1] = (__bf16)vv.y;
        o[2] = (__bf16)vv.z; o[3] = (__bf16)vv.w;
        ((bf16x4*)cbb)[i] = o;
        return;
    }
    const int id = blockIdx.x - 512;                 // 256 tasks
    const int t = id >> 3, ch = id & 7;
    // H8 row ch signs
    float sgn[8];
    #pragma unroll
    for (int k = 0; k < 8; ++k)
        sgn[k] = (__builtin_popcount(ch & k) & 1) ? -1.f : 1.f;
    // v[c] = sum_k sgn[k] * x[t, k*1024 + tid*4+c] * su[k*1024 + tid*4+c]
    float v[4] = {0.f, 0.f, 0.f, 0.f};
    #pragma unroll
    for (int k = 0; k < 8; ++k) {
        float4 xv = *(const float4*)(x + (size_t)t * IN_F + k * 1024 + tid * 4);
        float4 sv4 = *(const float4*)(su + k * 1024 + tid * 4);
        v[0] += sgn[k] * xv.x * sv4.x;
        v[1] += sgn[k] * xv.y * sv4.y;
        v[2] += sgn[k] * xv.z * sv4.z;
        v[3] += sgn[k] * xv.w * sv4.w;
    }
    fwht1024(v, st, tid);
    __bf16* dst = xh + (size_t)t * IN_F + ch * 1024;
    #pragma unroll
    for (int j = 0; j < 4; ++j)
        dst[tid + j * 256] = (__bf16)(v[j] * INV_SQRT_8192);
}

// ---------------- kernel 2: zpart = xh @ W^T (R11 champion, verbatim) -----
__global__ __launch_bounds__(512, 4)
void qgemm_kernel(const int* __restrict__ qidxs,
                  const __bf16* __restrict__ cb,
                  const __bf16* __restrict__ xh,
                  __bf16* __restrict__ zpart) {
    __shared__ __align__(16) __bf16 xt[TOKENS * KCHUNK];   // 64 KB
    const int ks = blockIdx.x & (KSPLIT - 1);
    const int nb = blockIdx.x >> 3;
    const int tid = threadIdx.x;
    const int wave = tid >> 6, lane = tid & 63;
    const int h = lane >> 5, lc = lane & 31;
    const int n = nb * 256 + wave * 32 + lc;

    // stage xh k-slice (32 tok x 1024 k) -> LDS, 16B chunks xor-swizzled
    #pragma unroll
    for (int i = 0; i < 8; ++i) {
        int f = i * 512 + tid, r = f >> 7, c = f & 127;
        i32x4 v = *(const i32x4*)(xh + (size_t)r * IN_F + ks * KCHUNK + c * 8);
        *(i32x4*)(xt + ((r * CH + (c ^ (r & 7))) << 3)) = v;
    }
    __syncthreads();    // the only barrier

    const int* qrow = qidxs + (size_t)n * (IN_F / 8) + ks * (KCHUNK / 8);

#if HAVE_BUF
    // SRD over the bf16 codebook (1 MB). aux=1 -> SC0: L1-bypass, L2-cached.
    __amdgpu_buffer_rsrc_t rsrc = __builtin_amdgcn_make_buffer_rsrc(
        (void*)cb, (short)0, 65536 * 16, 0x00020000);
    #define GA(ix, au) __builtin_bit_cast(bf16x8, \
        __builtin_amdgcn_raw_buffer_load_b128(rsrc, (ix) << 4, 0, au))
#else
    const bf16x8* cbv = (const bf16x8*)cb;
    #define GA(ix, au) (cbv[ix])
#endif

    f32x16 acc;
    #pragma unroll
    for (int i = 0; i < 16; ++i) acc[i] = 0.f;

    i32x4 iv[GROUPS];
    bf16x8 bfr[GROUPS][2];

    #pragma unroll
    for (int g = 0; g < DI; ++g)
        iv[g] = *(const i32x4*)(qrow + g * 4);
    #pragma unroll
    for (int g = 0; g < DG; ++g) {
        if (g & 1) {
            bfr[g][0] = GA(h ? iv[g][1] : iv[g][0], 1);
            bfr[g][1] = GA(h ? iv[g][3] : iv[g][2], 1);
        } else {
            bfr[g][0] = GA(h ? iv[g][1] : iv[g][0], 0);
            bfr[g][1] = GA(h ? iv[g][3] : iv[g][2], 0);
        }
    }

    #pragma unroll
    for (int g = 0; g < GROUPS; ++g) {
        if (g + DI < GROUPS)
            iv[g + DI] = *(const i32x4*)(qrow + (g + DI) * 4);
        if (g + DG < GROUPS) {
            if ((g + DG) & 1) {
                bfr[g + DG][0] = GA(h ? iv[g + DG][1] : iv[g + DG][0], 1);
                bfr[g + DG][1] = GA(h ? iv[g + DG][3] : iv[g + DG][2], 1);
            } else {
                bfr[g + DG][0] = GA(h ? iv[g + DG][1] : iv[g + DG][0], 0);
                bfr[g + DG][1] = GA(h ? iv[g + DG][3] : iv[g + DG][2], 0);
            }
        }
        #pragma unroll
        for (int sgi = 0; sgi < 2; ++sgi) {
            const int T = 2 * g + sgi;
            bf16x8 a = *(const bf16x8*)(xt +
                          ((lc * CH + ((2 * T + h) ^ (lc & 7))) << 3));
            acc = __builtin_amdgcn_mfma_f32_32x32x16_bf16(a, bfr[g][sgi],
                                                          acc, 0, 0, 0);
        }
    }

    // D[m=(r&3)+4h+8(r>>2)][n=lc] -> bf16 partials
    __bf16* zp = zpart + ((size_t)ks * TOKENS) * OUT_F + n;
    #pragma unroll
    for (int r = 0; r < 16; ++r) {
        int m = (r & 3) + 4 * h + 8 * (r >> 2);
        zp[(size_t)m * OUT_F] = (__bf16)acc[r];
    }
}

// ---- kernel 3: out = fused(ks-sum + H8 + H1024) * scale * sv -------------
__global__ __launch_bounds__(256)
void zsum_kernel(const __bf16* __restrict__ zpart, const float* __restrict__ sv,
                 const float* __restrict__ wscale, float* __restrict__ out) {
    __shared__ float st[1056];
    const int tid = threadIdx.x;
    const int t = blockIdx.x >> 3, ch = blockIdx.x & 7;  // 256 blocks
    float sgn[8];
    #pragma unroll
    for (int k = 0; k < 8; ++k)
        sgn[k] = (__builtin_popcount(ch & k) & 1) ? -1.f : 1.f;
    // acc[kk][c] = sum_ks zpart[ks, t, kk*1024 + tid*4+c]
    float a0[8] = {0,0,0,0,0,0,0,0}, a1[8] = {0,0,0,0,0,0,0,0};
    float a2[8] = {0,0,0,0,0,0,0,0}, a3[8] = {0,0,0,0,0,0,0,0};
    #pragma unroll
    for (int ks = 0; ks < KSPLIT; ++ks) {
        const __bf16* zr = zpart + ((size_t)(ks * TOKENS + t)) * OUT_F + tid * 4;
        #pragma unroll
        for (int kk = 0; kk < 8; ++kk) {
            bf16x4 b = *(const bf16x4*)(zr + kk * 1024);
            a0[kk] += (float)b[0]; a1[kk] += (float)b[1];
            a2[kk] += (float)b[2]; a3[kk] += (float)b[3];
        }
    }
    // H8 combine for this block's chunk ch
    float v[4] = {0.f, 0.f, 0.f, 0.f};
    #pragma unroll
    for (int kk = 0; kk < 8; ++kk) {
        v[0] += sgn[kk] * a0[kk];
        v[1] += sgn[kk] * a1[kk];
        v[2] += sgn[kk] * a2[kk];
        v[3] += sgn[kk] * a3[kk];
    }
    fwht1024(v, st, tid);
    const float sc = INV_SQRT_8192 * wscale[0];
    float* dst = out + (size_t)t * OUT_F + ch * 1024;
    const float* svp = sv + ch * 1024;
    #pragma unroll
    for (int j = 0; j < 4; ++j)
        dst[tid + j * 256] = v[j] * sc * svp[tid + j * 256];
}

extern "C" void kernel_launch(void* const* d_in, const int* in_sizes, int n_in,
                              void* d_out, int out_size, void* d_ws, size_t ws_size,
                              hipStream_t stream) {
    const float* x      = (const float*)d_in[0];   // (32, 8192)
    const float* cb     = (const float*)d_in[1];   // (65536, 8)
    const int*   qidxs  = (const int*)d_in[2];     // (8192, 1024)
    const float* su     = (const float*)d_in[3];   // (8192,)
    const float* sv     = (const float*)d_in[4];   // (8192,)
    const float* wscale = (const float*)d_in[5];   // scalar
    float* out = (float*)d_out;                    // (32, 8192) fp32

    char* ws = (char*)d_ws;
    __bf16* cb_bf16 = (__bf16*)ws;                               // 1 MB
    __bf16* xh      = (__bf16*)(ws + (1u << 20));                // 512 KB
    __bf16* zpart   = (__bf16*)(ws + (1u << 20) + (512u << 10)); // 4 MB bf16

    hipLaunchKernelGGL(prep_kernel, dim3(768), dim3(256), 0, stream,
                       cb, cb_bf16, x, su, xh);
    hipLaunchKernelGGL(qgemm_kernel, dim3(32 * KSPLIT), dim3(512), 0, stream,
                       qidxs, cb_bf16, xh, zpart);
    hipLaunchKernelGGL(zsum_kernel, dim3(256), dim3(256), 0, stream,
                       zpart, sv, wscale, out);
}